// Round 1
// baseline (904.593 us; speedup 1.0000x reference)
//
#include <hip/hip_runtime.h>
#include <hip/hip_bf16.h>
#include <cstdint>
#include <cstddef>

// ---- problem constants ----
#define VOCAB 50257
#define D_EMB 341
#define K_CTX 3
#define HID   1023
#define M_ROWS 2048      // S*B
#define KP    1024       // padded inner dim
#define NP1   1024       // padded N for GEMM1
#define NP2   50304      // padded vocab = 393*128

using short8 = __attribute__((ext_vector_type(8))) short;
using f32x4  = __attribute__((ext_vector_type(4))) float;

__device__ __forceinline__ void gload16(const void* g, void* l) {
  __builtin_amdgcn_global_load_lds(
      (const __attribute__((address_space(1))) unsigned int*)g,
      (__attribute__((address_space(3))) unsigned int*)l, 16, 0, 0);
}

__device__ __forceinline__ short f2bf(float v) {
  __hip_bfloat16 h = __float2bfloat16(v);
  return *reinterpret_cast<short*>(&h);
}

// ---------------------------------------------------------------------------
// x[m, j] for m = t*2 + b2, j in [0,1024). Torch-faithful reshape:
// flat = b2*1023 + j ; k = flat/682 ; b = (flat%682)/341 ; d = flat%341
// token = (t+k-3 >= 0) ? tokens[(t+k-3)*2 + b] : 0 ; val = embed[token*341+d]
// ---------------------------------------------------------------------------
__global__ void build_x(const int* __restrict__ tokens,
                        const float* __restrict__ embed,
                        short* __restrict__ x) {
  int idx = blockIdx.x * blockDim.x + threadIdx.x;   // < 2048*1024
  int m = idx >> 10;
  int j = idx & 1023;
  float v = 0.f;
  if (j < HID) {
    int t = m >> 1, b2 = m & 1;
    int flat = b2 * HID + j;
    int k = flat / (2 * D_EMB);
    int rem = flat - k * (2 * D_EMB);
    int b = (rem >= D_EMB) ? 1 : 0;
    int d = rem - b * D_EMB;
    int p = t + k - K_CTX;
    int tok = (p >= 0) ? tokens[p * 2 + b] : 0;
    v = embed[tok * D_EMB + d];
  }
  x[idx] = f2bf(v);
}

// ---------------------------------------------------------------------------
// dst[(n0+nn)*KP + k0+kk] = bf16(src[(k0+kk)*srcLd + n0+nn])  (zero-padded)
// grid.x = 16 * (dstRows/64); block = 256
// ---------------------------------------------------------------------------
__global__ void transpose_to_bf16(const float* __restrict__ src,
                                  short* __restrict__ dst,
                                  int srcK, int srcN, int srcLd) {
  __shared__ short tile[64][66];
  int bt = blockIdx.x;
  int kt = bt & 15;          // KP/64 = 16
  int nt = bt >> 4;
  int k0 = kt * 64, n0 = nt * 64;
  int tid = threadIdx.x;
  int sub = tid >> 6;        // 0..3
  int lo  = tid & 63;
#pragma unroll
  for (int i = 0; i < 16; ++i) {
    int kk = i * 4 + sub;
    int nn = lo;
    float v = 0.f;
    int gk = k0 + kk, gn = n0 + nn;
    if (gk < srcK && gn < srcN) v = src[gk * srcLd + gn];
    tile[kk][nn] = f2bf(v);
  }
  __syncthreads();
#pragma unroll
  for (int i = 0; i < 16; ++i) {
    int nn = i * 4 + sub;
    int kk = lo;
    dst[(size_t)(n0 + nn) * KP + (k0 + kk)] = tile[kk][nn];
  }
}

// ---------------------------------------------------------------------------
// C = A(M,KP) @ Bt(N,KP)^T ; 128x128 tile, BK=64, 4 waves (2x2), 16x16x32 MFMA
// SILU_BF16: out = bf16(silu(acc+bias)) into (.,1024)   else fp32 acc+bias,
// guarded store col < storeN, ldc row stride.
// ---------------------------------------------------------------------------
template <bool SILU_BF16>
__global__ __launch_bounds__(256, 2)
void gemm_bf16(const short* __restrict__ A, const short* __restrict__ Bt,
               const float* __restrict__ bias, int biasN,
               void* __restrict__ Cout, int ldc, int storeN, int MT) {
  __shared__ __align__(16) short As[128 * 64];
  __shared__ __align__(16) short Bs[128 * 64];

  int bid = blockIdx.x;
  int mt = bid % MT, nt = bid / MT;
  int bm = mt * 128, bn = nt * 128;
  int tid = threadIdx.x;
  int lane = tid & 63;
  int wid = tid >> 6;
  int wm = (wid >> 1) * 64, wn = (wid & 1) * 64;

  const short* ga = A + (size_t)(bm + (tid >> 3)) * KP + (tid & 7) * 8;
  const short* gb = Bt + (size_t)(bn + (tid >> 3)) * KP + (tid & 7) * 8;
  short* la = As + tid * 8;   // == (tid>>3)*64 + (tid&7)*8
  short* lb = Bs + tid * 8;

  f32x4 acc[4][4];
#pragma unroll
  for (int i = 0; i < 4; ++i)
#pragma unroll
    for (int j = 0; j < 4; ++j) acc[i][j] = f32x4{0.f, 0.f, 0.f, 0.f};

  int l16 = lane & 15;
  int kq = (lane >> 4) * 8;

  for (int k0 = 0; k0 < KP; k0 += 64) {
#pragma unroll
    for (int i = 0; i < 4; ++i) {
      gload16(ga + (size_t)i * 32 * KP + k0, la + i * 32 * 64);
      gload16(gb + (size_t)i * 32 * KP + k0, lb + i * 32 * 64);
    }
    __syncthreads();
#pragma unroll
    for (int ks = 0; ks < 2; ++ks) {
      short8 af[4], bfr[4];
      int ko = ks * 32 + kq;
#pragma unroll
      for (int i = 0; i < 4; ++i)
        af[i] = *reinterpret_cast<const short8*>(&As[(wm + i * 16 + l16) * 64 + ko]);
#pragma unroll
      for (int j = 0; j < 4; ++j)
        bfr[j] = *reinterpret_cast<const short8*>(&Bs[(wn + j * 16 + l16) * 64 + ko]);
#pragma unroll
      for (int i = 0; i < 4; ++i)
#pragma unroll
        for (int j = 0; j < 4; ++j)
          acc[i][j] = __builtin_amdgcn_mfma_f32_16x16x32_bf16(af[i], bfr[j], acc[i][j], 0, 0, 0);
    }
    __syncthreads();
  }

  // epilogue: C/D layout col = lane&15, row = (lane>>4)*4 + r
  int crow0 = (lane >> 4) * 4;
  int ccol = lane & 15;
#pragma unroll
  for (int i = 0; i < 4; ++i) {
#pragma unroll
    for (int j = 0; j < 4; ++j) {
      int colg = bn + wn + j * 16 + ccol;
      float bv = (colg < biasN) ? bias[colg] : 0.f;
#pragma unroll
      for (int r = 0; r < 4; ++r) {
        int rowg = bm + wm + i * 16 + crow0 + r;
        float v = acc[i][j][r] + bv;
        if constexpr (SILU_BF16) {
          v = v / (1.f + __expf(-v));
          ((short*)Cout)[(size_t)rowg * ldc + colg] = f2bf(v);
        } else {
          if (colg < storeN)
            ((float*)Cout)[(size_t)rowg * ldc + colg] = v;
        }
      }
    }
  }
}

// ---------------------------------------------------------------------------
extern "C" void kernel_launch(void* const* d_in, const int* in_sizes, int n_in,
                              void* d_out, int out_size, void* d_ws, size_t ws_size,
                              hipStream_t stream) {
  const int*   tokens = (const int*)d_in[0];
  const float* embed  = (const float*)d_in[1];
  const float* W1     = (const float*)d_in[2];
  const float* b1     = (const float*)d_in[3];
  const float* W2     = (const float*)d_in[4];
  const float* b2     = (const float*)d_in[5];
  float* out = (float*)d_out;

  char* ws = (char*)d_ws;
  short* W2t = (short*)ws;                                           // NP2 x KP
  short* x   = (short*)(ws + (size_t)NP2 * KP * 2);                  // M x KP
  short* h   = (short*)(ws + (size_t)NP2 * KP * 2 + (size_t)M_ROWS * KP * 2);
  short* W1t = (short*)(ws + (size_t)NP2 * KP * 2 + 2 * (size_t)M_ROWS * KP * 2);

  build_x<<<(M_ROWS * KP) / 256, 256, 0, stream>>>(tokens, embed, x);
  transpose_to_bf16<<<16 * (NP1 / 64), 256, 0, stream>>>(W1, W1t, HID, HID, HID);
  transpose_to_bf16<<<16 * (NP2 / 64), 256, 0, stream>>>(W2, W2t, HID, VOCAB, VOCAB);

  // h = silu(x @ W1 + b1), bf16 out (2048 x 1024, col 1023 == 0 by padding)
  gemm_bf16<true><<<16 * (NP1 / 128), 256, 0, stream>>>(
      x, W1t, b1, HID, h, KP, NP1, 16);

  // logits = h @ W2 + b2, fp32 out (2048 x 50257)
  gemm_bf16<false><<<16 * (NP2 / 128), 256, 0, stream>>>(
      h, W2t, b2, VOCAB, out, VOCAB, VOCAB, 16);
}